// Round 4
// baseline (1489.395 us; speedup 1.0000x reference)
//
#include <hip/hip_runtime.h>
#include <math.h>

#define NN 50000
#define EE 800000
#define EPS 1e-5f
#define SCAN_CH 196   // ceil(NN/256)

#define NEG_BIG (-1e30f)
#define RESCALE_THR 4.0f

#define LO_SCALE 2048.0f       // 2^11 exponent shift for the f16 lo plane
#define LO_INV   (1.0f/2048.0f)

typedef unsigned short u16;
typedef _Float16 f16x8 __attribute__((ext_vector_type(8)));
typedef float f32x4 __attribute__((ext_vector_type(4)));

__device__ __forceinline__ u16 f2h(float f) {
    _Float16 h = (_Float16)f;               // v_cvt_f16_f32, RNE
    return __builtin_bit_cast(u16, h);
}
__device__ __forceinline__ float h2f(u16 u) {
    return (float)__builtin_bit_cast(_Float16, u);
}

// ---------------------------------------------------------------------------
// CSR build: histogram -> 3-kernel parallel scan -> scatter (packs src+ea)
// ---------------------------------------------------------------------------
__global__ void hist_kernel(const int* __restrict__ dst, int* cnt) {
    int e = blockIdx.x * blockDim.x + threadIdx.x;
    if (e < EE) atomicAdd(&cnt[dst[e]], 1);
}

__global__ void scan_part(const int* __restrict__ cnt, int* __restrict__ part) {
    __shared__ int red[256];
    int b = blockIdx.x, t = threadIdx.x;
    int i = b * SCAN_CH + t;
    int v = (t < SCAN_CH && i < NN) ? cnt[i] : 0;
    red[t] = v;
    __syncthreads();
#pragma unroll
    for (int s = 128; s; s >>= 1) {
        if (t < s) red[t] += red[t + s];
        __syncthreads();
    }
    if (t == 0) part[b] = red[0];
}

__global__ void scan_block(int* part) {
    __shared__ int buf[2][256];
    int t = threadIdx.x;
    int v = part[t];
    int p = 0;
    buf[0][t] = v;
    __syncthreads();
#pragma unroll
    for (int off = 1; off < 256; off <<= 1) {
        buf[p ^ 1][t] = buf[p][t] + ((t >= off) ? buf[p][t - off] : 0);
        __syncthreads();
        p ^= 1;
    }
    part[t] = buf[p][t] - v;
}

__global__ void scan_final(int* __restrict__ cntcur, const int* __restrict__ part,
                           int* __restrict__ row_start) {
    __shared__ int buf[2][256];
    int b = blockIdx.x, t = threadIdx.x;
    int i = b * SCAN_CH + t;
    int v = (t < SCAN_CH && i < NN) ? cntcur[i] : 0;
    int p = 0;
    buf[0][t] = v;
    __syncthreads();
#pragma unroll
    for (int off = 1; off < 256; off <<= 1) {
        buf[p ^ 1][t] = buf[p][t] + ((t >= off) ? buf[p][t - off] : 0);
        __syncthreads();
        p ^= 1;
    }
    if (t < SCAN_CH && i < NN) {
        int pos = part[b] + buf[p][t] - v;   // exclusive
        row_start[i] = pos;
        cntcur[i] = pos;                     // scatter cursor
    }
    if (b == 0 && t == 0) row_start[NN] = EE;
}

__global__ void scatter_kernel(const int* __restrict__ ei, const float* __restrict__ ea,
                               int* cursor, int2* __restrict__ edge_pack) {
    int e = blockIdx.x * blockDim.x + threadIdx.x;
    if (e < EE) {
        int d = ei[EE + e];
        int pos = atomicAdd(&cursor[d], 1);
        edge_pack[pos] = make_int2(ei[e], __float_as_int(ea[e]));
    }
}

// ---------------------------------------------------------------------------
// fp32 -> f16 hi + scaled-lo split of a dense array (vectorized), n4 = elems/4
// ---------------------------------------------------------------------------
__global__ void split_f32(const float* __restrict__ in, u16* __restrict__ hi,
                          u16* __restrict__ lo, int n4) {
    int i = blockIdx.x * blockDim.x + threadIdx.x;
    if (i >= n4) return;
    float4 v = ((const float4*)in)[i];
    ushort4 h, l;
    h.x = f2h(v.x); l.x = f2h((v.x - h2f(h.x)) * LO_SCALE);
    h.y = f2h(v.y); l.y = f2h((v.y - h2f(h.y)) * LO_SCALE);
    h.z = f2h(v.z); l.z = f2h((v.z - h2f(h.z)) * LO_SCALE);
    h.w = f2h(v.w); l.w = f2h((v.w - h2f(h.w)) * LO_SCALE);
    ((ushort4*)hi)[i] = h;
    ((ushort4*)lo)[i] = l;
}

// ---------------------------------------------------------------------------
// Weight convert: 9 layers of [Wl|Wr] (each [128][128], row-major K x N)
// -> transposed Wt[layer][256][128] (n-major, k contiguous) in f16 hi/lo.
// Wt[n][k] = (n<128 ? Wl[k][n] : Wr[k][n-128])
// ---------------------------------------------------------------------------
__global__ void conv_w(const float* __restrict__ l1Wl, const float* __restrict__ l1Wr,
                       const float* __restrict__ midWl, const float* __restrict__ midWr,
                       u16* __restrict__ Wh, u16* __restrict__ Wlo) {
    int tid = blockIdx.x * 256 + threadIdx.x;
    if (tid >= 9 * 256 * 128) return;
    int L = tid >> 15;            // /32768
    int rem = tid & 32767;
    int n = rem >> 7, k = rem & 127;
    const float* WL;
    const float* WR;
    if (L == 0) { WL = l1Wl; WR = l1Wr; }
    else {
        WL = midWl + (size_t)(L - 1) * 16384;
        WR = midWr + (size_t)(L - 1) * 16384;
    }
    float w = (n < 128) ? WL[k * 128 + n] : WR[k * 128 + (n - 128)];
    u16 h = f2h(w);
    Wh[tid] = h;
    Wlo[tid] = f2h((w - h2f(h)) * LO_SCALE);
}

// ---------------------------------------------------------------------------
// MFMA f16 split GEMM: C[M x 256] fp32 = A[M x 128] @ W[128 x 256]
// A as f16 hi + scaled-lo [M][128]; W transposed Wt[256][128] hi + scaled-lo.
// accH = Ah*Wh; accL = Al'*Wh + Ah*Wl'  (Al' = (A-Ah)*2^11, same for Wl')
// C = accH + accL * 2^-11.  Error ~2^-22 relative (dropped Al'*Wl' term).
// Uses __builtin_amdgcn_mfma_f32_16x16x32_f16 (no inline asm).
// Fragment addressing (m89/m97-verified family):
//   A: lane l -> row (l&15), k = (l>>4)*8 + i ; B from Wt[n][k]: col (l&15),
//   same k slots; C/D: col = lane&15, row = (lane>>4)*4 + reg.
// Block: 512 thr = 8 waves = 4 row-tiles x 2 col-halves; wave: 16 rows x 128 cols.
// No LDS, no barriers; W panel (128 KB/layer) stays L2-resident.
// ---------------------------------------------------------------------------
__global__ __launch_bounds__(512) void gemm_mfma(const u16* __restrict__ Ah,
                                                 const u16* __restrict__ Al,
                                                 const u16* __restrict__ Bh,
                                                 const u16* __restrict__ Bl,
                                                 float* __restrict__ C) {
    int wib  = threadIdx.x >> 6;
    int lane = threadIdx.x & 63;
    int row0 = blockIdx.x * 64 + (wib >> 1) * 16;
    if (row0 >= NN) return;
    int ch = (wib & 1) << 7;      // column half: 0 (Wl) or 128 (Wr)
    int lr = lane & 15;
    int kg = lane >> 4;

    // A fragments for full K=128, held in registers (hi+lo = 32 VGPRs)
    size_t aoff = (size_t)(row0 + lr) * 128 + (size_t)(kg * 8);
    f16x8 ah[4], al[4];
#pragma unroll
    for (int ks = 0; ks < 4; ++ks) {
        ah[ks] = *(const f16x8*)(Ah + aoff + ks * 32);
        al[ks] = *(const f16x8*)(Al + aoff + ks * 32);
    }

    size_t boff = (size_t)(ch + lr) * 128 + (size_t)(kg * 8);
#pragma unroll
    for (int np = 0; np < 4; ++np) {
        const u16* b0h = Bh + boff + (size_t)(2 * np) * 2048;   // col ch+32np+lr
        const u16* b1h = b0h + 2048;                            // col +16
        const u16* b0l = Bl + boff + (size_t)(2 * np) * 2048;
        const u16* b1l = b0l + 2048;
        f16x8 h0[4], h1[4], l0[4], l1[4];
#pragma unroll
        for (int ks = 0; ks < 4; ++ks) {
            h0[ks] = *(const f16x8*)(b0h + ks * 32);
            h1[ks] = *(const f16x8*)(b1h + ks * 32);
            l0[ks] = *(const f16x8*)(b0l + ks * 32);
            l1[ks] = *(const f16x8*)(b1l + ks * 32);
        }
        f32x4 aH0 = (f32x4){0.f, 0.f, 0.f, 0.f};
        f32x4 aH1 = (f32x4){0.f, 0.f, 0.f, 0.f};
        f32x4 aL0 = (f32x4){0.f, 0.f, 0.f, 0.f};
        f32x4 aL1 = (f32x4){0.f, 0.f, 0.f, 0.f};
#pragma unroll
        for (int ks = 0; ks < 4; ++ks) {
            aH0 = __builtin_amdgcn_mfma_f32_16x16x32_f16(ah[ks], h0[ks], aH0, 0, 0, 0);
            aH1 = __builtin_amdgcn_mfma_f32_16x16x32_f16(ah[ks], h1[ks], aH1, 0, 0, 0);
            aL0 = __builtin_amdgcn_mfma_f32_16x16x32_f16(al[ks], h0[ks], aL0, 0, 0, 0);
            aL1 = __builtin_amdgcn_mfma_f32_16x16x32_f16(al[ks], h1[ks], aL1, 0, 0, 0);
            aL0 = __builtin_amdgcn_mfma_f32_16x16x32_f16(ah[ks], l0[ks], aL0, 0, 0, 0);
            aL1 = __builtin_amdgcn_mfma_f32_16x16x32_f16(ah[ks], l1[ks], aL1, 0, 0, 0);
        }
        float* cp = C + (size_t)(row0 + kg * 4) * 256 + ch + lr + np * 32;
#pragma unroll
        for (int r = 0; r < 4; ++r) {
            cp[(size_t)r * 256]      = fmaf(aL0[r], LO_INV, aH0[r]);
            cp[(size_t)r * 256 + 16] = fmaf(aL1[r], LO_INV, aH1[r]);
        }
    }
}

// ---------------------------------------------------------------------------
// Small fp32 GEMM for layer 10 (A stride 128, nc<=64)
// ---------------------------------------------------------------------------
__global__ __launch_bounds__(256) void gemm_tile(const float* __restrict__ A,
                                                 const float* __restrict__ B,
                                                 float* __restrict__ C,
                                                 int M, int nc, int ldb, int ldc, int coff) {
    __shared__ float As[128][64];
    __shared__ float Bs[128][64];
    int t  = threadIdx.x;
    int bm = blockIdx.x * 64;
    int bn = blockIdx.y * 64;
    {
        int k4 = (t & 31) << 2;
        int r0 = t >> 5;
#pragma unroll
        for (int pass = 0; pass < 8; ++pass) {
            int row = r0 + pass * 8;
            int gm  = bm + row;
            float4 v = make_float4(0.f, 0.f, 0.f, 0.f);
            if (gm < M) v = *(const float4*)(A + (size_t)gm * 128 + k4);
            As[k4 + 0][row] = v.x; As[k4 + 1][row] = v.y;
            As[k4 + 2][row] = v.z; As[k4 + 3][row] = v.w;
        }
    }
    {
        int c4 = (t & 15) << 2;
        int kr = t >> 4;
#pragma unroll
        for (int pass = 0; pass < 8; ++pass) {
            int k  = kr + pass * 16;
            int gc = bn + c4;
            float4 v = make_float4(0.f, 0.f, 0.f, 0.f);
            if (gc < nc) v = *(const float4*)(B + (size_t)k * ldb + gc);
            *(float4*)&Bs[k][c4] = v;
        }
    }
    __syncthreads();

    int tx = t & 15, ty = t >> 4;
    int m0 = ty * 4, c0 = tx * 4;
    float acc[4][4] = {{0.f}};
#pragma unroll 8
    for (int k = 0; k < 128; ++k) {
        float4 av = *(const float4*)&As[k][m0];
        float4 bv = *(const float4*)&Bs[k][c0];
        float a4[4] = {av.x, av.y, av.z, av.w};
        float b4[4] = {bv.x, bv.y, bv.z, bv.w};
#pragma unroll
        for (int i = 0; i < 4; ++i)
#pragma unroll
            for (int j = 0; j < 4; ++j) acc[i][j] = fmaf(a4[i], b4[j], acc[i][j]);
    }
#pragma unroll
    for (int i = 0; i < 4; ++i) {
        int gm = bm + m0 + i;
        int gc = bn + c0;
        if (gm < M && gc < nc) {
            *(float4*)(C + (size_t)gm * ldc + coff + gc) =
                make_float4(acc[i][0], acc[i][1], acc[i][2], acc[i][3]);
        }
    }
}

// ---------------------------------------------------------------------------
// Node kernel layers 1-9: half-wave per edge, float4 per lane, DPP head
// reduction, defer-max online softmax. Epilogue emits f16 hi + scaled-lo
// (next layer's GEMM A operand) and optionally fp32 h (layer 9 -> gemm_tile).
// ---------------------------------------------------------------------------
__device__ __forceinline__ float dpp_add8(float x) {
    int t;
    t = __builtin_amdgcn_update_dpp(0, __float_as_int(x), 0xB1, 0xf, 0xf, true);
    x += __int_as_float(t);
    t = __builtin_amdgcn_update_dpp(0, __float_as_int(x), 0x4E, 0xf, 0xf, true);
    x += __int_as_float(t);
    t = __builtin_amdgcn_update_dpp(0, __float_as_int(x), 0x141, 0xf, 0xf, true);
    x += __int_as_float(t);
    return x;
}

__global__ __launch_bounds__(256) void node_agg_128(const float* __restrict__ xlr,
                                                    const int* __restrict__ row_start,
                                                    const int2* __restrict__ epack,
                                                    const float* __restrict__ We,
                                                    const float* __restrict__ att,
                                                    const float* __restrict__ bias,
                                                    const float* __restrict__ bng,
                                                    const float* __restrict__ bnb,
                                                    const float* __restrict__ bnm,
                                                    const float* __restrict__ bnv,
                                                    u16* __restrict__ ahi,
                                                    u16* __restrict__ alo,
                                                    int wf32,
                                                    float* __restrict__ hout) {
    int wave = (blockIdx.x * blockDim.x + threadIdx.x) >> 6;
    int lane = threadIdx.x & 63;
    if (wave >= NN) return;
    int half = lane >> 5;
    int c0   = (lane & 31) << 2;

    const float L2E = 1.44269504f;
    const float4 xr4 = *(const float4*)(xlr + (size_t)wave * 256 + 128 + c0);
    const float4 we4 = *(const float4*)(We + c0);
    const float4 at4 = *(const float4*)(att + c0);
    float4 a6, a4;
    a6.x = 0.6f * L2E * at4.x; a4.x = 0.4f * L2E * at4.x;
    a6.y = 0.6f * L2E * at4.y; a4.y = 0.4f * L2E * at4.y;
    a6.z = 0.6f * L2E * at4.z; a4.z = 0.4f * L2E * at4.z;
    a6.w = 0.6f * L2E * at4.w; a4.w = 0.4f * L2E * at4.w;

    int beg = row_start[wave], end = row_start[wave + 1];
    int lastE = end - 1;

    float mx0 = NEG_BIG, sm0 = 0.f;
    float mx1 = NEG_BIG, sm1 = 0.f;
    float4 ac0 = make_float4(0.f, 0.f, 0.f, 0.f);
    float4 ac1 = make_float4(0.f, 0.f, 0.f, 0.f);

    auto score = [&](float eav, const float4& xv) -> float {
        float m0 = xv.x + fmaf(eav, we4.x, xr4.x);
        float m1 = xv.y + fmaf(eav, we4.y, xr4.y);
        float m2 = xv.z + fmaf(eav, we4.z, xr4.z);
        float m3 = xv.w + fmaf(eav, we4.w, xr4.w);
        float p = fmaf(a6.x, m0, a4.x * fabsf(m0));
        p = fmaf(a6.y, m1, fmaf(a4.y, fabsf(m1), p));
        p = fmaf(a6.z, m2, fmaf(a4.z, fabsf(m2), p));
        p = fmaf(a6.w, m3, fmaf(a4.w, fabsf(m3), p));
        return dpp_add8(p);
    };

    auto upd = [&](float& mx, float& sm, float4& ac, float p, const float4& xv) {
        float d = p - mx;
        if (__ballot(d > RESCALE_THR)) {
            float nm = fmaxf(mx, p);
            float sc = exp2f(mx - nm);
            float w  = exp2f(p - nm);
            sm = fmaf(sm, sc, w);
            ac.x = fmaf(ac.x, sc, w * xv.x);
            ac.y = fmaf(ac.y, sc, w * xv.y);
            ac.z = fmaf(ac.z, sc, w * xv.z);
            ac.w = fmaf(ac.w, sc, w * xv.w);
            mx = nm;
        } else {
            float w = exp2f(d);
            sm += w;
            ac.x = fmaf(w, xv.x, ac.x);
            ac.y = fmaf(w, xv.y, ac.y);
            ac.z = fmaf(w, xv.z, ac.z);
            ac.w = fmaf(w, xv.w, ac.w);
        }
    };

    int j = beg;
    for (; j + 3 < end; j += 4) {
        int2 pkA = epack[j + half];
        int2 pkB = epack[j + 2 + half];
        float4 xA = *(const float4*)(xlr + ((size_t)pkA.x << 8) + c0);
        float4 xB = *(const float4*)(xlr + ((size_t)pkB.x << 8) + c0);
        float pA = score(__int_as_float(pkA.y), xA);
        float pB = score(__int_as_float(pkB.y), xB);
        upd(mx0, sm0, ac0, pA, xA);
        upd(mx1, sm1, ac1, pB, xB);
    }
    if (j < end) {
        int jeA = j + half;       bool dA = jeA > lastE; if (dA) jeA = lastE;
        int jeB = j + 2 + half;   bool dB = jeB > lastE; if (dB) jeB = lastE;
        int2 pkA = epack[jeA];
        int2 pkB = epack[jeB];
        float4 xA = *(const float4*)(xlr + ((size_t)pkA.x << 8) + c0);
        float4 xB = *(const float4*)(xlr + ((size_t)pkB.x << 8) + c0);
        float pA = score(__int_as_float(pkA.y), xA);
        float pB = score(__int_as_float(pkB.y), xB);
        pA = dA ? NEG_BIG : pA;
        pB = dB ? NEG_BIG : pB;
        upd(mx0, sm0, ac0, pA, xA);
        upd(mx1, sm1, ac1, pB, xB);
    }

    float Mx = fmaxf(mx0, mx1);
    float s0 = exp2f(mx0 - Mx), s1 = exp2f(mx1 - Mx);
    float sm = fmaf(sm0, s0, sm1 * s1);
    float4 ac;
    ac.x = fmaf(ac0.x, s0, ac1.x * s1);
    ac.y = fmaf(ac0.y, s0, ac1.y * s1);
    ac.z = fmaf(ac0.z, s0, ac1.z * s1);
    ac.w = fmaf(ac0.w, s0, ac1.w * s1);

    float  Mo  = __shfl_xor(Mx, 32);
    float  smo = __shfl_xor(sm, 32);
    float4 aco;
    aco.x = __shfl_xor(ac.x, 32);
    aco.y = __shfl_xor(ac.y, 32);
    aco.z = __shfl_xor(ac.z, 32);
    aco.w = __shfl_xor(ac.w, 32);
    float Mn = fmaxf(Mx, Mo);
    float ss = exp2f(Mx - Mn), so = exp2f(Mo - Mn);
    sm   = fmaf(sm, ss, smo * so);
    ac.x = fmaf(ac.x, ss, aco.x * so);
    ac.y = fmaf(ac.y, ss, aco.y * so);
    ac.z = fmaf(ac.z, ss, aco.z * so);
    ac.w = fmaf(ac.w, ss, aco.w * so);

    if (half == 0) {
        float inv = 1.f / (sm + 1e-16f);
        const float4 b4  = *(const float4*)(bias + c0);
        const float4 g4  = *(const float4*)(bng + c0);
        const float4 bb4 = *(const float4*)(bnb + c0);
        const float4 m4  = *(const float4*)(bnm + c0);
        const float4 v4  = *(const float4*)(bnv + c0);
        float4 y;
        y.x = fmaxf(fmaf(ac.x, inv, b4.x), 0.f);
        y.y = fmaxf(fmaf(ac.y, inv, b4.y), 0.f);
        y.z = fmaxf(fmaf(ac.z, inv, b4.z), 0.f);
        y.w = fmaxf(fmaf(ac.w, inv, b4.w), 0.f);
        y.x = (y.x - m4.x) * rsqrtf(v4.x + EPS) * g4.x + bb4.x;
        y.y = (y.y - m4.y) * rsqrtf(v4.y + EPS) * g4.y + bb4.y;
        y.z = (y.z - m4.z) * rsqrtf(v4.z + EPS) * g4.z + bb4.z;
        y.w = (y.w - m4.w) * rsqrtf(v4.w + EPS) * g4.w + bb4.w;

        ushort4 hh, ll;
        hh.x = f2h(y.x); ll.x = f2h((y.x - h2f(hh.x)) * LO_SCALE);
        hh.y = f2h(y.y); ll.y = f2h((y.y - h2f(hh.y)) * LO_SCALE);
        hh.z = f2h(y.z); ll.z = f2h((y.z - h2f(hh.z)) * LO_SCALE);
        hh.w = f2h(y.w); ll.w = f2h((y.w - h2f(hh.w)) * LO_SCALE);
        *(ushort4*)(ahi + (size_t)wave * 128 + c0) = hh;
        *(ushort4*)(alo + (size_t)wave * 128 + c0) = ll;
        if (wf32) *(float4*)(hout + (size_t)wave * 128 + c0) = y;
    }
}

// ---------------------------------------------------------------------------
// Layer 10: half-wave per node. H=1, C=32, xlr10: [N][64]. 2 states, unroll-2.
// ---------------------------------------------------------------------------
__global__ __launch_bounds__(256) void node_agg_l10(const float* __restrict__ xlr,
                                                    const int* __restrict__ row_start,
                                                    const int2* __restrict__ epack,
                                                    const float* __restrict__ We,
                                                    const float* __restrict__ att,
                                                    const float* __restrict__ bias,
                                                    const float* __restrict__ bng,
                                                    const float* __restrict__ bnb,
                                                    const float* __restrict__ bnm,
                                                    const float* __restrict__ bnv,
                                                    const float* __restrict__ linW,
                                                    const float* __restrict__ linb,
                                                    float* __restrict__ out) {
    int n = (blockIdx.x * blockDim.x + threadIdx.x) >> 5;
    int c = threadIdx.x & 31;
    if (n >= NN) return;

    const float L2E = 1.44269504f;
    float xr = xlr[(size_t)n * 64 + 32 + c];
    float we = We[c];
    float a6 = 0.6f * L2E * att[c], a4 = 0.4f * L2E * att[c];
    int beg = row_start[n], end = row_start[n + 1];

    float mxs[2] = {-INFINITY, -INFINITY};
    float sms[2] = {0.f, 0.f};
    float acs[2] = {0.f, 0.f};

    auto upd = [&](int st, float xl, float eav) {
        float m = xl + fmaf(eav, we, xr);
        float p = fmaf(a6, m, a4 * fabsf(m));
#pragma unroll
        for (int off = 16; off; off >>= 1) p += __shfl_xor(p, off);
        float nm = fmaxf(mxs[st], p);
        float sc = exp2f(mxs[st] - nm);
        float w  = exp2f(p - nm);
        sms[st] = fmaf(sms[st], sc, w);
        acs[st] = fmaf(acs[st], sc, w * xl);
        mxs[st] = nm;
    };

    int j = beg;
    for (; j + 1 < end; j += 2) {
        int2 p0 = epack[j], p1 = epack[j + 1];
        float x0 = xlr[((size_t)p0.x << 6) + c];
        float x1 = xlr[((size_t)p1.x << 6) + c];
        upd(0, x0, __int_as_float(p0.y));
        upd(1, x1, __int_as_float(p1.y));
    }
    if (j < end) {
        int2 pk = epack[j];
        upd(0, xlr[((size_t)pk.x << 6) + c], __int_as_float(pk.y));
    }

    float M = fmaxf(mxs[0], mxs[1]);
    float sm = 0.f, acc = 0.f;
#pragma unroll
    for (int st = 0; st < 2; ++st) {
        float sc = (mxs[st] == -INFINITY) ? 0.f : exp2f(mxs[st] - M);
        sm  = fmaf(sms[st], sc, sm);
        acc = fmaf(acs[st], sc, acc);
    }

    float y = acc / (sm + 1e-16f) + bias[c];
    y = fmaxf(y, 0.f);
    y = (y - bnm[c]) * rsqrtf(bnv[c] + EPS) * bng[c] + bnb[c];

    float t0 = y * linW[c * 4 + 0];
    float t1 = y * linW[c * 4 + 1];
    float t2 = y * linW[c * 4 + 2];
    float t3 = y * linW[c * 4 + 3];
#pragma unroll
    for (int off = 16; off; off >>= 1) {
        t0 += __shfl_xor(t0, off);
        t1 += __shfl_xor(t1, off);
        t2 += __shfl_xor(t2, off);
        t3 += __shfl_xor(t3, off);
    }
    if (c == 0) {
        out[(size_t)n * 4 + 0] = t0 + linb[0];
        out[(size_t)n * 4 + 1] = t1 + linb[1];
        out[(size_t)n * 4 + 2] = t2 + linb[2];
        out[(size_t)n * 4 + 3] = t3 + linb[3];
    }
}

// ---------------------------------------------------------------------------
extern "C" void kernel_launch(void* const* d_in, const int* in_sizes, int n_in,
                              void* d_out, int out_size, void* d_ws, size_t ws_size,
                              hipStream_t stream) {
    const float* x      = (const float*)d_in[0];
    const int*   ei     = (const int*)d_in[1];
    const float* ea     = (const float*)d_in[2];
    const float* l1_Wl  = (const float*)d_in[3];
    const float* l1_Wr  = (const float*)d_in[4];
    const float* l1_We  = (const float*)d_in[5];
    const float* l1_att = (const float*)d_in[6];
    const float* l1_b   = (const float*)d_in[7];
    const float* mid_Wl = (const float*)d_in[8];
    const float* mid_Wr = (const float*)d_in[9];
    const float* mid_We = (const float*)d_in[10];
    const float* mid_att= (const float*)d_in[11];
    const float* mid_b  = (const float*)d_in[12];
    const float* l10_Wl = (const float*)d_in[13];
    const float* l10_Wr = (const float*)d_in[14];
    const float* l10_We = (const float*)d_in[15];
    const float* l10_att= (const float*)d_in[16];
    const float* l10_b  = (const float*)d_in[17];
    const float* bn_g   = (const float*)d_in[18];
    const float* bn_b   = (const float*)d_in[19];
    const float* bn_m   = (const float*)d_in[20];
    const float* bn_v   = (const float*)d_in[21];
    const float* bn10_g = (const float*)d_in[22];
    const float* bn10_b = (const float*)d_in[23];
    const float* bn10_m = (const float*)d_in[24];
    const float* bn10_v = (const float*)d_in[25];
    const float* lin_W  = (const float*)d_in[26];
    const float* lin_b  = (const float*)d_in[27];

    char* ws = (char*)d_ws;
    auto take = [&](size_t bytes) { char* p = ws; ws += (bytes + 255) & ~size_t(255); return p; };
    int*   row_start  = (int*)  take(sizeof(int) * (NN + 1));
    int*   cursor     = (int*)  take(sizeof(int) * NN);
    int*   part       = (int*)  take(sizeof(int) * 256);
    int2*  epack      = (int2*) take(sizeof(int2) * EE);
    float* xlr        = (float*)take(sizeof(float) * (size_t)NN * 256);
    float* h0         = (float*)take(sizeof(float) * (size_t)NN * 128);
    u16*   Ahi        = (u16*)  take(sizeof(u16) * (size_t)NN * 128);
    u16*   Alo        = (u16*)  take(sizeof(u16) * (size_t)NN * 128);
    u16*   Wthi       = (u16*)  take(sizeof(u16) * 9 * 256 * 128);
    u16*   Wtlo       = (u16*)  take(sizeof(u16) * 9 * 256 * 128);

    // --- CSR build ---
    hipMemsetAsync(cursor, 0, sizeof(int) * NN, stream);
    hist_kernel<<<EE / 256, 256, 0, stream>>>(ei + EE, cursor);
    scan_part<<<256, 256, 0, stream>>>(cursor, part);
    scan_block<<<1, 256, 0, stream>>>(part);
    scan_final<<<256, 256, 0, stream>>>(cursor, part, row_start);
    scatter_kernel<<<EE / 256, 256, 0, stream>>>(ei, ea, cursor, epack);

    // --- one-time conversions ---
    split_f32<<<(NN * 128 / 4 + 255) / 256, 256, 0, stream>>>(x, Ahi, Alo, NN * 128 / 4);
    conv_w<<<(9 * 256 * 128 + 255) / 256, 256, 0, stream>>>(l1_Wl, l1_Wr, mid_Wl, mid_Wr,
                                                            Wthi, Wtlo);

    const int GBM = (NN + 63) / 64;  // 782 blocks of 8 waves

    // --- layer 1 ---
    gemm_mfma<<<GBM, 512, 0, stream>>>(Ahi, Alo, Wthi, Wtlo, xlr);
    node_agg_128<<<(NN * 64) / 256, 256, 0, stream>>>(
        xlr, row_start, epack, l1_We, l1_att, l1_b,
        bn_g, bn_b, bn_m, bn_v, Ahi, Alo, 0, h0);

    // --- layers 2-9 ---
    for (int i = 0; i < 8; ++i) {
        gemm_mfma<<<GBM, 512, 0, stream>>>(Ahi, Alo,
                                           Wthi + (size_t)(i + 1) * 32768,
                                           Wtlo + (size_t)(i + 1) * 32768, xlr);
        node_agg_128<<<(NN * 64) / 256, 256, 0, stream>>>(
            xlr, row_start, epack,
            mid_We + (size_t)i * 128, mid_att + (size_t)i * 128, mid_b + (size_t)i * 128,
            bn_g + (size_t)(i + 1) * 128, bn_b + (size_t)(i + 1) * 128,
            bn_m + (size_t)(i + 1) * 128, bn_v + (size_t)(i + 1) * 128,
            Ahi, Alo, (i == 7) ? 1 : 0, h0);
    }

    // --- layer 10 (xlr reused as [N][64]) ---
    const int MB = (NN + 63) / 64;  // 782
    dim3 g1(MB, 1);
    gemm_tile<<<g1, 256, 0, stream>>>(h0, l10_Wl, xlr, NN, 32, 32, 64, 0);
    gemm_tile<<<g1, 256, 0, stream>>>(h0, l10_Wr, xlr, NN, 32, 32, 64, 32);
    node_agg_l10<<<(NN * 32 + 255) / 256, 256, 0, stream>>>(
        xlr, row_start, epack, l10_We, l10_att, l10_b,
        bn10_g, bn10_b, bn10_m, bn10_v, lin_W, lin_b, (float*)d_out);
}

// Round 5
// 1248.670 us; speedup vs baseline: 1.1928x; 1.1928x over previous
//
#include <hip/hip_runtime.h>
#include <math.h>

#define NN 50000
#define EE 800000
#define EPS 1e-5f
#define SCAN_CH 196   // ceil(NN/256)

#define NEG_BIG (-1e30f)
#define RESCALE_THR 4.0f

#define LO_SCALE 2048.0f       // 2^11 exponent shift for the f16 lo plane
#define LO_INV   (1.0f/2048.0f)

typedef unsigned short u16;
typedef _Float16 f16x8 __attribute__((ext_vector_type(8)));
typedef float f32x4 __attribute__((ext_vector_type(4)));

__device__ __forceinline__ u16 f2h(float f) {
    _Float16 h = (_Float16)f;               // v_cvt_f16_f32, RNE
    return __builtin_bit_cast(u16, h);
}
__device__ __forceinline__ float h2f(u16 u) {
    return (float)__builtin_bit_cast(_Float16, u);
}

// ---------------------------------------------------------------------------
// CSR build: histogram -> 3-kernel parallel scan -> scatter (packs src+ea)
// ---------------------------------------------------------------------------
__global__ void hist_kernel(const int* __restrict__ dst, int* cnt) {
    int e = blockIdx.x * blockDim.x + threadIdx.x;
    if (e < EE) atomicAdd(&cnt[dst[e]], 1);
}

__global__ void scan_part(const int* __restrict__ cnt, int* __restrict__ part) {
    __shared__ int red[256];
    int b = blockIdx.x, t = threadIdx.x;
    int i = b * SCAN_CH + t;
    int v = (t < SCAN_CH && i < NN) ? cnt[i] : 0;
    red[t] = v;
    __syncthreads();
#pragma unroll
    for (int s = 128; s; s >>= 1) {
        if (t < s) red[t] += red[t + s];
        __syncthreads();
    }
    if (t == 0) part[b] = red[0];
}

__global__ void scan_block(int* part) {
    __shared__ int buf[2][256];
    int t = threadIdx.x;
    int v = part[t];
    int p = 0;
    buf[0][t] = v;
    __syncthreads();
#pragma unroll
    for (int off = 1; off < 256; off <<= 1) {
        buf[p ^ 1][t] = buf[p][t] + ((t >= off) ? buf[p][t - off] : 0);
        __syncthreads();
        p ^= 1;
    }
    part[t] = buf[p][t] - v;
}

__global__ void scan_final(int* __restrict__ cntcur, const int* __restrict__ part,
                           int* __restrict__ row_start) {
    __shared__ int buf[2][256];
    int b = blockIdx.x, t = threadIdx.x;
    int i = b * SCAN_CH + t;
    int v = (t < SCAN_CH && i < NN) ? cntcur[i] : 0;
    int p = 0;
    buf[0][t] = v;
    __syncthreads();
#pragma unroll
    for (int off = 1; off < 256; off <<= 1) {
        buf[p ^ 1][t] = buf[p][t] + ((t >= off) ? buf[p][t - off] : 0);
        __syncthreads();
        p ^= 1;
    }
    if (t < SCAN_CH && i < NN) {
        int pos = part[b] + buf[p][t] - v;   // exclusive
        row_start[i] = pos;
        cntcur[i] = pos;                     // scatter cursor
    }
    if (b == 0 && t == 0) row_start[NN] = EE;
}

__global__ void scatter_kernel(const int* __restrict__ ei, const float* __restrict__ ea,
                               int* cursor, int2* __restrict__ edge_pack) {
    int e = blockIdx.x * blockDim.x + threadIdx.x;
    if (e < EE) {
        int d = ei[EE + e];
        int pos = atomicAdd(&cursor[d], 1);
        edge_pack[pos] = make_int2(ei[e], __float_as_int(ea[e]));
    }
}

// ---------------------------------------------------------------------------
// fp32 -> f16 hi + scaled-lo split of a dense array (vectorized), n4 = elems/4
// ---------------------------------------------------------------------------
__global__ void split_f32(const float* __restrict__ in, u16* __restrict__ hi,
                          u16* __restrict__ lo, int n4) {
    int i = blockIdx.x * blockDim.x + threadIdx.x;
    if (i >= n4) return;
    float4 v = ((const float4*)in)[i];
    ushort4 h, l;
    h.x = f2h(v.x); l.x = f2h((v.x - h2f(h.x)) * LO_SCALE);
    h.y = f2h(v.y); l.y = f2h((v.y - h2f(h.y)) * LO_SCALE);
    h.z = f2h(v.z); l.z = f2h((v.z - h2f(h.z)) * LO_SCALE);
    h.w = f2h(v.w); l.w = f2h((v.w - h2f(h.w)) * LO_SCALE);
    ((ushort4*)hi)[i] = h;
    ((ushort4*)lo)[i] = l;
}

// ---------------------------------------------------------------------------
// Weight convert: 9 layers of [Wl|Wr] (each [128][128], row-major K x N)
// -> transposed Wt[layer][256][128] (n-major, k contiguous) in f16 hi/lo.
// Wt[n][k] = (n<128 ? Wl[k][n] : Wr[k][n-128])
// ---------------------------------------------------------------------------
__global__ void conv_w(const float* __restrict__ l1Wl, const float* __restrict__ l1Wr,
                       const float* __restrict__ midWl, const float* __restrict__ midWr,
                       u16* __restrict__ Wh, u16* __restrict__ Wlo) {
    int tid = blockIdx.x * 256 + threadIdx.x;
    if (tid >= 9 * 256 * 128) return;
    int L = tid >> 15;            // /32768
    int rem = tid & 32767;
    int n = rem >> 7, k = rem & 127;
    const float* WL;
    const float* WR;
    if (L == 0) { WL = l1Wl; WR = l1Wr; }
    else {
        WL = midWl + (size_t)(L - 1) * 16384;
        WR = midWr + (size_t)(L - 1) * 16384;
    }
    float w = (n < 128) ? WL[k * 128 + n] : WR[k * 128 + (n - 128)];
    u16 h = f2h(w);
    Wh[tid] = h;
    Wlo[tid] = f2h((w - h2f(h)) * LO_SCALE);
}

// ---------------------------------------------------------------------------
// MFMA f16 split GEMM: C[M x 256] fp32 = A[M x 128] @ W[128 x 256]
// accH = Ah*Wh; accL = Al'*Wh + Ah*Wl'; C = accH + accL*2^-11 (err ~2^-22).
//
// Round-5 restructure (fix for the round-4 latency disaster, VGPR=60):
//   each wave owns a FIXED 32-col group; its 16 B fragments (64 VGPR) are
//   loaded ONCE (loop-invariant -> LICM keeps them in registers), then 8
//   row-tiles of A stream past with double-buffered prefetch. 192 MFMA/wave,
//   B L2-traffic 4x lower, independent acc chains per row-tile.
// Block: 256 thr = 4 waves = 4 col-groups (128 cols); grid (391, 2).
// Fragment addressing unchanged from round 4 (verified absmax 1.0).
// ---------------------------------------------------------------------------
__global__ __launch_bounds__(256) void gemm_mfma(const u16* __restrict__ Ah,
                                                 const u16* __restrict__ Al,
                                                 const u16* __restrict__ Bh,
                                                 const u16* __restrict__ Bl,
                                                 float* __restrict__ C) {
    int w    = threadIdx.x >> 6;
    int lane = threadIdx.x & 63;
    int lr = lane & 15;
    int kg = lane >> 4;
    int rowbase = blockIdx.x * 128;
    int colbase = blockIdx.y * 128 + w * 32;

    // ---- B fragments: loop-invariant, held in registers (64 VGPR) ----
    f16x8 bh[2][4], bl[2][4];
#pragma unroll
    for (int ct = 0; ct < 2; ++ct) {
        size_t boff = (size_t)(colbase + ct * 16 + lr) * 128 + (size_t)(kg * 8);
#pragma unroll
        for (int ks = 0; ks < 4; ++ks) {
            bh[ct][ks] = *(const f16x8*)(Bh + boff + ks * 32);
            bl[ct][ks] = *(const f16x8*)(Bl + boff + ks * 32);
        }
    }

    // ---- A row-tile 0 (clamped load; stores are guarded) ----
    auto aoff_of = [&](int rt) {
        int arow = rowbase + rt * 16 + lr;
        if (arow >= NN) arow = NN - 1;
        return (size_t)arow * 128 + (size_t)(kg * 8);
    };
    f16x8 ahc[4], alc[4], ahn[4], aln[4];
    {
        size_t ao = aoff_of(0);
#pragma unroll
        for (int ks = 0; ks < 4; ++ks) {
            ahc[ks] = *(const f16x8*)(Ah + ao + ks * 32);
            alc[ks] = *(const f16x8*)(Al + ao + ks * 32);
        }
    }

#pragma unroll
    for (int rt = 0; rt < 8; ++rt) {
        // prefetch next row-tile while computing this one
        if (rt < 7) {
            size_t ao = aoff_of(rt + 1);
#pragma unroll
            for (int ks = 0; ks < 4; ++ks) {
                ahn[ks] = *(const f16x8*)(Ah + ao + ks * 32);
                aln[ks] = *(const f16x8*)(Al + ao + ks * 32);
            }
        }

        f32x4 aH[2], aL[2];
#pragma unroll
        for (int ct = 0; ct < 2; ++ct) {
            aH[ct] = (f32x4){0.f, 0.f, 0.f, 0.f};
            aL[ct] = (f32x4){0.f, 0.f, 0.f, 0.f};
        }
#pragma unroll
        for (int ks = 0; ks < 4; ++ks) {
#pragma unroll
            for (int ct = 0; ct < 2; ++ct) {
                aH[ct] = __builtin_amdgcn_mfma_f32_16x16x32_f16(ahc[ks], bh[ct][ks], aH[ct], 0, 0, 0);
                aL[ct] = __builtin_amdgcn_mfma_f32_16x16x32_f16(alc[ks], bh[ct][ks], aL[ct], 0, 0, 0);
                aL[ct] = __builtin_amdgcn_mfma_f32_16x16x32_f16(ahc[ks], bl[ct][ks], aL[ct], 0, 0, 0);
            }
        }

        int crow0 = rowbase + rt * 16 + kg * 4;
#pragma unroll
        for (int ct = 0; ct < 2; ++ct) {
            float* cp = C + (size_t)crow0 * 256 + colbase + ct * 16 + lr;
#pragma unroll
            for (int r = 0; r < 4; ++r) {
                if (crow0 + r < NN)
                    cp[(size_t)r * 256] = fmaf(aL[ct][r], LO_INV, aH[ct][r]);
            }
        }

        if (rt < 7) {
#pragma unroll
            for (int ks = 0; ks < 4; ++ks) { ahc[ks] = ahn[ks]; alc[ks] = aln[ks]; }
        }
    }
}

// ---------------------------------------------------------------------------
// Small fp32 GEMM for layer 10 (A stride 128, nc<=64)
// ---------------------------------------------------------------------------
__global__ __launch_bounds__(256) void gemm_tile(const float* __restrict__ A,
                                                 const float* __restrict__ B,
                                                 float* __restrict__ C,
                                                 int M, int nc, int ldb, int ldc, int coff) {
    __shared__ float As[128][64];
    __shared__ float Bs[128][64];
    int t  = threadIdx.x;
    int bm = blockIdx.x * 64;
    int bn = blockIdx.y * 64;
    {
        int k4 = (t & 31) << 2;
        int r0 = t >> 5;
#pragma unroll
        for (int pass = 0; pass < 8; ++pass) {
            int row = r0 + pass * 8;
            int gm  = bm + row;
            float4 v = make_float4(0.f, 0.f, 0.f, 0.f);
            if (gm < M) v = *(const float4*)(A + (size_t)gm * 128 + k4);
            As[k4 + 0][row] = v.x; As[k4 + 1][row] = v.y;
            As[k4 + 2][row] = v.z; As[k4 + 3][row] = v.w;
        }
    }
    {
        int c4 = (t & 15) << 2;
        int kr = t >> 4;
#pragma unroll
        for (int pass = 0; pass < 8; ++pass) {
            int k  = kr + pass * 16;
            int gc = bn + c4;
            float4 v = make_float4(0.f, 0.f, 0.f, 0.f);
            if (gc < nc) v = *(const float4*)(B + (size_t)k * ldb + gc);
            *(float4*)&Bs[k][c4] = v;
        }
    }
    __syncthreads();

    int tx = t & 15, ty = t >> 4;
    int m0 = ty * 4, c0 = tx * 4;
    float acc[4][4] = {{0.f}};
#pragma unroll 8
    for (int k = 0; k < 128; ++k) {
        float4 av = *(const float4*)&As[k][m0];
        float4 bv = *(const float4*)&Bs[k][c0];
        float a4[4] = {av.x, av.y, av.z, av.w};
        float b4[4] = {bv.x, bv.y, bv.z, bv.w};
#pragma unroll
        for (int i = 0; i < 4; ++i)
#pragma unroll
            for (int j = 0; j < 4; ++j) acc[i][j] = fmaf(a4[i], b4[j], acc[i][j]);
    }
#pragma unroll
    for (int i = 0; i < 4; ++i) {
        int gm = bm + m0 + i;
        int gc = bn + c0;
        if (gm < M && gc < nc) {
            *(float4*)(C + (size_t)gm * ldc + coff + gc) =
                make_float4(acc[i][0], acc[i][1], acc[i][2], acc[i][3]);
        }
    }
}

// ---------------------------------------------------------------------------
// Node kernel layers 1-9: half-wave per edge, float4 per lane, DPP head
// reduction, defer-max online softmax. Epilogue emits f16 hi + scaled-lo
// (next layer's GEMM A operand) and optionally fp32 h (layer 9 -> gemm_tile).
// ---------------------------------------------------------------------------
__device__ __forceinline__ float dpp_add8(float x) {
    int t;
    t = __builtin_amdgcn_update_dpp(0, __float_as_int(x), 0xB1, 0xf, 0xf, true);
    x += __int_as_float(t);
    t = __builtin_amdgcn_update_dpp(0, __float_as_int(x), 0x4E, 0xf, 0xf, true);
    x += __int_as_float(t);
    t = __builtin_amdgcn_update_dpp(0, __float_as_int(x), 0x141, 0xf, 0xf, true);
    x += __int_as_float(t);
    return x;
}

__global__ __launch_bounds__(256) void node_agg_128(const float* __restrict__ xlr,
                                                    const int* __restrict__ row_start,
                                                    const int2* __restrict__ epack,
                                                    const float* __restrict__ We,
                                                    const float* __restrict__ att,
                                                    const float* __restrict__ bias,
                                                    const float* __restrict__ bng,
                                                    const float* __restrict__ bnb,
                                                    const float* __restrict__ bnm,
                                                    const float* __restrict__ bnv,
                                                    u16* __restrict__ ahi,
                                                    u16* __restrict__ alo,
                                                    int wf32,
                                                    float* __restrict__ hout) {
    int wave = (blockIdx.x * blockDim.x + threadIdx.x) >> 6;
    int lane = threadIdx.x & 63;
    if (wave >= NN) return;
    int half = lane >> 5;
    int c0   = (lane & 31) << 2;

    const float L2E = 1.44269504f;
    const float4 xr4 = *(const float4*)(xlr + (size_t)wave * 256 + 128 + c0);
    const float4 we4 = *(const float4*)(We + c0);
    const float4 at4 = *(const float4*)(att + c0);
    float4 a6, a4;
    a6.x = 0.6f * L2E * at4.x; a4.x = 0.4f * L2E * at4.x;
    a6.y = 0.6f * L2E * at4.y; a4.y = 0.4f * L2E * at4.y;
    a6.z = 0.6f * L2E * at4.z; a4.z = 0.4f * L2E * at4.z;
    a6.w = 0.6f * L2E * at4.w; a4.w = 0.4f * L2E * at4.w;

    int beg = row_start[wave], end = row_start[wave + 1];
    int lastE = end - 1;

    float mx0 = NEG_BIG, sm0 = 0.f;
    float mx1 = NEG_BIG, sm1 = 0.f;
    float4 ac0 = make_float4(0.f, 0.f, 0.f, 0.f);
    float4 ac1 = make_float4(0.f, 0.f, 0.f, 0.f);

    auto score = [&](float eav, const float4& xv) -> float {
        float m0 = xv.x + fmaf(eav, we4.x, xr4.x);
        float m1 = xv.y + fmaf(eav, we4.y, xr4.y);
        float m2 = xv.z + fmaf(eav, we4.z, xr4.z);
        float m3 = xv.w + fmaf(eav, we4.w, xr4.w);
        float p = fmaf(a6.x, m0, a4.x * fabsf(m0));
        p = fmaf(a6.y, m1, fmaf(a4.y, fabsf(m1), p));
        p = fmaf(a6.z, m2, fmaf(a4.z, fabsf(m2), p));
        p = fmaf(a6.w, m3, fmaf(a4.w, fabsf(m3), p));
        return dpp_add8(p);
    };

    auto upd = [&](float& mx, float& sm, float4& ac, float p, const float4& xv) {
        float d = p - mx;
        if (__ballot(d > RESCALE_THR)) {
            float nm = fmaxf(mx, p);
            float sc = exp2f(mx - nm);
            float w  = exp2f(p - nm);
            sm = fmaf(sm, sc, w);
            ac.x = fmaf(ac.x, sc, w * xv.x);
            ac.y = fmaf(ac.y, sc, w * xv.y);
            ac.z = fmaf(ac.z, sc, w * xv.z);
            ac.w = fmaf(ac.w, sc, w * xv.w);
            mx = nm;
        } else {
            float w = exp2f(d);
            sm += w;
            ac.x = fmaf(w, xv.x, ac.x);
            ac.y = fmaf(w, xv.y, ac.y);
            ac.z = fmaf(w, xv.z, ac.z);
            ac.w = fmaf(w, xv.w, ac.w);
        }
    };

    int j = beg;
    for (; j + 3 < end; j += 4) {
        int2 pkA = epack[j + half];
        int2 pkB = epack[j + 2 + half];
        float4 xA = *(const float4*)(xlr + ((size_t)pkA.x << 8) + c0);
        float4 xB = *(const float4*)(xlr + ((size_t)pkB.x << 8) + c0);
        float pA = score(__int_as_float(pkA.y), xA);
        float pB = score(__int_as_float(pkB.y), xB);
        upd(mx0, sm0, ac0, pA, xA);
        upd(mx1, sm1, ac1, pB, xB);
    }
    if (j < end) {
        int jeA = j + half;       bool dA = jeA > lastE; if (dA) jeA = lastE;
        int jeB = j + 2 + half;   bool dB = jeB > lastE; if (dB) jeB = lastE;
        int2 pkA = epack[jeA];
        int2 pkB = epack[jeB];
        float4 xA = *(const float4*)(xlr + ((size_t)pkA.x << 8) + c0);
        float4 xB = *(const float4*)(xlr + ((size_t)pkB.x << 8) + c0);
        float pA = score(__int_as_float(pkA.y), xA);
        float pB = score(__int_as_float(pkB.y), xB);
        pA = dA ? NEG_BIG : pA;
        pB = dB ? NEG_BIG : pB;
        upd(mx0, sm0, ac0, pA, xA);
        upd(mx1, sm1, ac1, pB, xB);
    }

    float Mx = fmaxf(mx0, mx1);
    float s0 = exp2f(mx0 - Mx), s1 = exp2f(mx1 - Mx);
    float sm = fmaf(sm0, s0, sm1 * s1);
    float4 ac;
    ac.x = fmaf(ac0.x, s0, ac1.x * s1);
    ac.y = fmaf(ac0.y, s0, ac1.y * s1);
    ac.z = fmaf(ac0.z, s0, ac1.z * s1);
    ac.w = fmaf(ac0.w, s0, ac1.w * s1);

    float  Mo  = __shfl_xor(Mx, 32);
    float  smo = __shfl_xor(sm, 32);
    float4 aco;
    aco.x = __shfl_xor(ac.x, 32);
    aco.y = __shfl_xor(ac.y, 32);
    aco.z = __shfl_xor(ac.z, 32);
    aco.w = __shfl_xor(ac.w, 32);
    float Mn = fmaxf(Mx, Mo);
    float ss = exp2f(Mx - Mn), so = exp2f(Mo - Mn);
    sm   = fmaf(sm, ss, smo * so);
    ac.x = fmaf(ac.x, ss, aco.x * so);
    ac.y = fmaf(ac.y, ss, aco.y * so);
    ac.z = fmaf(ac.z, ss, aco.z * so);
    ac.w = fmaf(ac.w, ss, aco.w * so);

    if (half == 0) {
        float inv = 1.f / (sm + 1e-16f);
        const float4 b4  = *(const float4*)(bias + c0);
        const float4 g4  = *(const float4*)(bng + c0);
        const float4 bb4 = *(const float4*)(bnb + c0);
        const float4 m4  = *(const float4*)(bnm + c0);
        const float4 v4  = *(const float4*)(bnv + c0);
        float4 y;
        y.x = fmaxf(fmaf(ac.x, inv, b4.x), 0.f);
        y.y = fmaxf(fmaf(ac.y, inv, b4.y), 0.f);
        y.z = fmaxf(fmaf(ac.z, inv, b4.z), 0.f);
        y.w = fmaxf(fmaf(ac.w, inv, b4.w), 0.f);
        y.x = (y.x - m4.x) * rsqrtf(v4.x + EPS) * g4.x + bb4.x;
        y.y = (y.y - m4.y) * rsqrtf(v4.y + EPS) * g4.y + bb4.y;
        y.z = (y.z - m4.z) * rsqrtf(v4.z + EPS) * g4.z + bb4.z;
        y.w = (y.w - m4.w) * rsqrtf(v4.w + EPS) * g4.w + bb4.w;

        ushort4 hh, ll;
        hh.x = f2h(y.x); ll.x = f2h((y.x - h2f(hh.x)) * LO_SCALE);
        hh.y = f2h(y.y); ll.y = f2h((y.y - h2f(hh.y)) * LO_SCALE);
        hh.z = f2h(y.z); ll.z = f2h((y.z - h2f(hh.z)) * LO_SCALE);
        hh.w = f2h(y.w); ll.w = f2h((y.w - h2f(hh.w)) * LO_SCALE);
        *(ushort4*)(ahi + (size_t)wave * 128 + c0) = hh;
        *(ushort4*)(alo + (size_t)wave * 128 + c0) = ll;
        if (wf32) *(float4*)(hout + (size_t)wave * 128 + c0) = y;
    }
}

// ---------------------------------------------------------------------------
// Layer 10: half-wave per node. H=1, C=32, xlr10: [N][64]. 2 states, unroll-2.
// ---------------------------------------------------------------------------
__global__ __launch_bounds__(256) void node_agg_l10(const float* __restrict__ xlr,
                                                    const int* __restrict__ row_start,
                                                    const int2* __restrict__ epack,
                                                    const float* __restrict__ We,
                                                    const float* __restrict__ att,
                                                    const float* __restrict__ bias,
                                                    const float* __restrict__ bng,
                                                    const float* __restrict__ bnb,
                                                    const float* __restrict__ bnm,
                                                    const float* __restrict__ bnv,
                                                    const float* __restrict__ linW,
                                                    const float* __restrict__ linb,
                                                    float* __restrict__ out) {
    int n = (blockIdx.x * blockDim.x + threadIdx.x) >> 5;
    int c = threadIdx.x & 31;
    if (n >= NN) return;

    const float L2E = 1.44269504f;
    float xr = xlr[(size_t)n * 64 + 32 + c];
    float we = We[c];
    float a6 = 0.6f * L2E * att[c], a4 = 0.4f * L2E * att[c];
    int beg = row_start[n], end = row_start[n + 1];

    float mxs[2] = {-INFINITY, -INFINITY};
    float sms[2] = {0.f, 0.f};
    float acs[2] = {0.f, 0.f};

    auto upd = [&](int st, float xl, float eav) {
        float m = xl + fmaf(eav, we, xr);
        float p = fmaf(a6, m, a4 * fabsf(m));
#pragma unroll
        for (int off = 16; off; off >>= 1) p += __shfl_xor(p, off);
        float nm = fmaxf(mxs[st], p);
        float sc = exp2f(mxs[st] - nm);
        float w  = exp2f(p - nm);
        sms[st] = fmaf(sms[st], sc, w);
        acs[st] = fmaf(acs[st], sc, w * xl);
        mxs[st] = nm;
    };

    int j = beg;
    for (; j + 1 < end; j += 2) {
        int2 p0 = epack[j], p1 = epack[j + 1];
        float x0 = xlr[((size_t)p0.x << 6) + c];
        float x1 = xlr[((size_t)p1.x << 6) + c];
        upd(0, x0, __int_as_float(p0.y));
        upd(1, x1, __int_as_float(p1.y));
    }
    if (j < end) {
        int2 pk = epack[j];
        upd(0, xlr[((size_t)pk.x << 6) + c], __int_as_float(pk.y));
    }

    float M = fmaxf(mxs[0], mxs[1]);
    float sm = 0.f, acc = 0.f;
#pragma unroll
    for (int st = 0; st < 2; ++st) {
        float sc = (mxs[st] == -INFINITY) ? 0.f : exp2f(mxs[st] - M);
        sm  = fmaf(sms[st], sc, sm);
        acc = fmaf(acs[st], sc, acc);
    }

    float y = acc / (sm + 1e-16f) + bias[c];
    y = fmaxf(y, 0.f);
    y = (y - bnm[c]) * rsqrtf(bnv[c] + EPS) * bng[c] + bnb[c];

    float t0 = y * linW[c * 4 + 0];
    float t1 = y * linW[c * 4 + 1];
    float t2 = y * linW[c * 4 + 2];
    float t3 = y * linW[c * 4 + 3];
#pragma unroll
    for (int off = 16; off; off >>= 1) {
        t0 += __shfl_xor(t0, off);
        t1 += __shfl_xor(t1, off);
        t2 += __shfl_xor(t2, off);
        t3 += __shfl_xor(t3, off);
    }
    if (c == 0) {
        out[(size_t)n * 4 + 0] = t0 + linb[0];
        out[(size_t)n * 4 + 1] = t1 + linb[1];
        out[(size_t)n * 4 + 2] = t2 + linb[2];
        out[(size_t)n * 4 + 3] = t3 + linb[3];
    }
}

// ---------------------------------------------------------------------------
extern "C" void kernel_launch(void* const* d_in, const int* in_sizes, int n_in,
                              void* d_out, int out_size, void* d_ws, size_t ws_size,
                              hipStream_t stream) {
    const float* x      = (const float*)d_in[0];
    const int*   ei     = (const int*)d_in[1];
    const float* ea     = (const float*)d_in[2];
    const float* l1_Wl  = (const float*)d_in[3];
    const float* l1_Wr  = (const float*)d_in[4];
    const float* l1_We  = (const float*)d_in[5];
    const float* l1_att = (const float*)d_in[6];
    const float* l1_b   = (const float*)d_in[7];
    const float* mid_Wl = (const float*)d_in[8];
    const float* mid_Wr = (const float*)d_in[9];
    const float* mid_We = (const float*)d_in[10];
    const float* mid_att= (const float*)d_in[11];
    const float* mid_b  = (const float*)d_in[12];
    const float* l10_Wl = (const float*)d_in[13];
    const float* l10_Wr = (const float*)d_in[14];
    const float* l10_We = (const float*)d_in[15];
    const float* l10_att= (const float*)d_in[16];
    const float* l10_b  = (const float*)d_in[17];
    const float* bn_g   = (const float*)d_in[18];
    const float* bn_b   = (const float*)d_in[19];
    const float* bn_m   = (const float*)d_in[20];
    const float* bn_v   = (const float*)d_in[21];
    const float* bn10_g = (const float*)d_in[22];
    const float* bn10_b = (const float*)d_in[23];
    const float* bn10_m = (const float*)d_in[24];
    const float* bn10_v = (const float*)d_in[25];
    const float* lin_W  = (const float*)d_in[26];
    const float* lin_b  = (const float*)d_in[27];

    char* ws = (char*)d_ws;
    auto take = [&](size_t bytes) { char* p = ws; ws += (bytes + 255) & ~size_t(255); return p; };
    int*   row_start  = (int*)  take(sizeof(int) * (NN + 1));
    int*   cursor     = (int*)  take(sizeof(int) * NN);
    int*   part       = (int*)  take(sizeof(int) * 256);
    int2*  epack      = (int2*) take(sizeof(int2) * EE);
    float* xlr        = (float*)take(sizeof(float) * (size_t)NN * 256);
    float* h0         = (float*)take(sizeof(float) * (size_t)NN * 128);
    u16*   Ahi        = (u16*)  take(sizeof(u16) * (size_t)NN * 128);
    u16*   Alo        = (u16*)  take(sizeof(u16) * (size_t)NN * 128);
    u16*   Wthi       = (u16*)  take(sizeof(u16) * 9 * 256 * 128);
    u16*   Wtlo       = (u16*)  take(sizeof(u16) * 9 * 256 * 128);

    // --- CSR build ---
    hipMemsetAsync(cursor, 0, sizeof(int) * NN, stream);
    hist_kernel<<<EE / 256, 256, 0, stream>>>(ei + EE, cursor);
    scan_part<<<256, 256, 0, stream>>>(cursor, part);
    scan_block<<<1, 256, 0, stream>>>(part);
    scan_final<<<256, 256, 0, stream>>>(cursor, part, row_start);
    scatter_kernel<<<EE / 256, 256, 0, stream>>>(ei, ea, cursor, epack);

    // --- one-time conversions ---
    split_f32<<<(NN * 128 / 4 + 255) / 256, 256, 0, stream>>>(x, Ahi, Alo, NN * 128 / 4);
    conv_w<<<(9 * 256 * 128 + 255) / 256, 256, 0, stream>>>(l1_Wl, l1_Wr, mid_Wl, mid_Wr,
                                                            Wthi, Wtlo);

    const int GBM = (NN + 127) / 128;  // 391 row-blocks
    dim3 gmm(GBM, 2);

    // --- layer 1 ---
    gemm_mfma<<<gmm, 256, 0, stream>>>(Ahi, Alo, Wthi, Wtlo, xlr);
    node_agg_128<<<(NN * 64) / 256, 256, 0, stream>>>(
        xlr, row_start, epack, l1_We, l1_att, l1_b,
        bn_g, bn_b, bn_m, bn_v, Ahi, Alo, 0, h0);

    // --- layers 2-9 ---
    for (int i = 0; i < 8; ++i) {
        gemm_mfma<<<gmm, 256, 0, stream>>>(Ahi, Alo,
                                           Wthi + (size_t)(i + 1) * 32768,
                                           Wtlo + (size_t)(i + 1) * 32768, xlr);
        node_agg_128<<<(NN * 64) / 256, 256, 0, stream>>>(
            xlr, row_start, epack,
            mid_We + (size_t)i * 128, mid_att + (size_t)i * 128, mid_b + (size_t)i * 128,
            bn_g + (size_t)(i + 1) * 128, bn_b + (size_t)(i + 1) * 128,
            bn_m + (size_t)(i + 1) * 128, bn_v + (size_t)(i + 1) * 128,
            Ahi, Alo, (i == 7) ? 1 : 0, h0);
    }

    // --- layer 10 (xlr reused as [N][64]) ---
    const int MB = (NN + 63) / 64;  // 782
    dim3 g1(MB, 1);
    gemm_tile<<<g1, 256, 0, stream>>>(h0, l10_Wl, xlr, NN, 32, 32, 64, 0);
    gemm_tile<<<g1, 256, 0, stream>>>(h0, l10_Wr, xlr, NN, 32, 32, 64, 32);
    node_agg_l10<<<(NN * 32 + 255) / 256, 256, 0, stream>>>(
        xlr, row_start, epack, l10_We, l10_att, l10_b,
        bn10_g, bn10_b, bn10_m, bn10_v, lin_W, lin_b, (float*)d_out);
}